// Round 12
// baseline (29.309 us; speedup 1.0000x reference)
//
#include <hip/hip_runtime.h>

// out[b,u] = tanh( exp( max_i x[b,i]*W[i,u] ) - 1 + bias[u] )
// exp monotonic -> max commutes -> max-times "GEMM" + transcendental epilogue.
//
// R12: 2D register tile (2 rows x 2 units x 2 k = 16 products per ~2 operand
// insts). R4-R11 post-mortem: lane=unit designs deliver x at 1-2 products per
// narrow s_load through the single per-CU scalar unit -> 4-8x oversubscribed.
// Here x (SGPR, s_load_x16) is reused over 2 units, W (LDS b64, 2-way=free)
// over 2 rows; VALU finally the busiest pipe.
//   Block = 8 waves; wave owns 2 rows x 128 units, full k.
//   W streamed in 16KB chunks (BK=32) via double-buffered global_load_lds.
//   Grid 512 = 2 blocks/CU, 4 waves/SIMD. One barrier per chunk.

#define BATCH 2048
#define INDIM 512
#define UNITS 512

#define BK  32    // k per LDS chunk
#define UT  128   // units per block (lane owns 2 adjacent)
#define RPW 2     // rows per wave
#define NW  8     // waves per block -> 16 rows per block

typedef float f16v __attribute__((ext_vector_type(16)));

__global__ __launch_bounds__(512, 4) void maxexp_kernel(
    const float* __restrict__ x,     // [BATCH][INDIM]
    const float* __restrict__ W,     // [INDIM][UNITS]
    const float* __restrict__ bias,  // [UNITS]
    float* __restrict__ out)         // [BATCH][UNITS]
{
    __shared__ float wlds[2][BK][UT];   // 2 x 16 KB

    // bijective XCD swizzle: XCD (f&7) owns 16 contiguous row-groups x all ut.
    const int f    = blockIdx.x;                 // 0..511
    const int g    = (f & 7) * 64 + (f >> 3);    // bijective 0..511
    const int ut   = g & 3;                      // u-tile 0..3
    const int rowg = g >> 2;                     // 0..127
    const int u0   = ut * UT;
    const int b0   = rowg * (NW * RPW);          // 16 rows per block

    const int tid  = threadIdx.x;
    const int lane = tid & 63;
    const int wv   = __builtin_amdgcn_readfirstlane(tid >> 6);  // 0..7

    const float* xr0 = x + (size_t)(b0 + 2 * wv)     * INDIM;   // uniform
    const float* xr1 = x + (size_t)(b0 + 2 * wv + 1) * INDIM;   // uniform

    // stage chunk c into wlds[buf]: 8 waves x 2 instrs x 1KB (lane>>5 picks row)
#define STAGE(buf_, c_)                                                        \
    {                                                                          \
        _Pragma("unroll")                                                      \
        for (int j = 0; j < 2; ++j) {                                          \
            const int kr = 4 * wv + 2 * j;                                     \
            const float* src_ = W + (size_t)((c_) * BK + kr + (lane >> 5)) * UNITS \
                                + u0 + 4 * (lane & 31);                        \
            __builtin_amdgcn_global_load_lds(                                  \
                (const __attribute__((address_space(1))) unsigned int*)src_,   \
                (__attribute__((address_space(3))) unsigned int*)&wlds[buf_][kr][0], \
                16, 0, 0);                                                     \
        }                                                                      \
    }

    float a00 = -3.4e38f, a01 = -3.4e38f, a10 = -3.4e38f, a11 = -3.4e38f;

    STAGE(0, 0);
    __syncthreads();   // barrier drains vmcnt -> chunk 0 staged

    const int NCH = INDIM / BK;   // 16
#pragma unroll 1
    for (int c = 0; c < NCH; ++c) {
        const int buf = c & 1;
        if (c + 1 < NCH) STAGE(buf ^ 1, c + 1);

        // x for this chunk: 4 x s_load_dwordx16 (wave-uniform -> SGPRs)
        const f16v x0a = *reinterpret_cast<const f16v*>(xr0 + c * BK);
        const f16v x0b = *reinterpret_cast<const f16v*>(xr0 + c * BK + 16);
        const f16v x1a = *reinterpret_cast<const f16v*>(xr1 + c * BK);
        const f16v x1b = *reinterpret_cast<const f16v*>(xr1 + c * BK + 16);

#pragma unroll
        for (int kp = 0; kp < BK / 2; ++kp) {
            const float2 wA = *reinterpret_cast<const float2*>(&wlds[buf][2 * kp][2 * lane]);
            const float2 wB = *reinterpret_cast<const float2*>(&wlds[buf][2 * kp + 1][2 * lane]);
            const float xe0 = (kp < 8) ? x0a[(2 * kp) & 15]     : x0b[(2 * kp) & 15];
            const float xo0 = (kp < 8) ? x0a[(2 * kp + 1) & 15] : x0b[(2 * kp + 1) & 15];
            const float xe1 = (kp < 8) ? x1a[(2 * kp) & 15]     : x1b[(2 * kp) & 15];
            const float xo1 = (kp < 8) ? x1a[(2 * kp + 1) & 15] : x1b[(2 * kp + 1) & 15];
            a00 = fmaxf(fmaxf(a00, xe0 * wA.x), xo0 * wB.x);   // v_max3
            a01 = fmaxf(fmaxf(a01, xe0 * wA.y), xo0 * wB.y);
            a10 = fmaxf(fmaxf(a10, xe1 * wA.x), xo1 * wB.x);
            a11 = fmaxf(fmaxf(a11, xe1 * wA.y), xo1 * wB.y);
        }

        __syncthreads();   // all waves done reading buf; staged buf^1 drained
    }

    // epilogue: tanh(exp(m) - 1 + bias), float2 stores (units 2lane, 2lane+1)
    const float2 bv = *reinterpret_cast<const float2*>(bias + u0 + 2 * lane);
    {
        const float p0 = __expf(a00) - 1.0f + bv.x;
        const float p1 = __expf(a01) - 1.0f + bv.y;
        float2 o;
        o.x = 1.0f - 2.0f / (__expf(2.0f * p0) + 1.0f);
        o.y = 1.0f - 2.0f / (__expf(2.0f * p1) + 1.0f);
        *reinterpret_cast<float2*>(out + (size_t)(b0 + 2 * wv) * UNITS + u0 + 2 * lane) = o;
    }
    {
        const float p0 = __expf(a10) - 1.0f + bv.x;
        const float p1 = __expf(a11) - 1.0f + bv.y;
        float2 o;
        o.x = 1.0f - 2.0f / (__expf(2.0f * p0) + 1.0f);
        o.y = 1.0f - 2.0f / (__expf(2.0f * p1) + 1.0f);
        *reinterpret_cast<float2*>(out + (size_t)(b0 + 2 * wv + 1) * UNITS + u0 + 2 * lane) = o;
    }
#undef STAGE
}

extern "C" void kernel_launch(void* const* d_in, const int* in_sizes, int n_in,
                              void* d_out, int out_size, void* d_ws, size_t ws_size,
                              hipStream_t stream) {
    const float* x    = (const float*)d_in[0];
    const float* W    = (const float*)d_in[1];
    const float* bias = (const float*)d_in[2];
    float* out = (float*)d_out;

    dim3 grid(512);    // 128 row-groups x 4 u-tiles; 2 blocks/CU
    dim3 block(512);   // 8 waves
    maxexp_kernel<<<grid, block, 0, stream>>>(x, W, bias, out);
}